// Round 1
// baseline (295.291 us; speedup 1.0000x reference)
//
#include <hip/hip_runtime.h>
#include <cmath>

#ifndef M_PI
#define M_PI 3.14159265358979323846
#endif

// Problem constants (fixed by setup_inputs in the reference)
#define B_ 8
#define F_ 3
#define H_ 224
#define W_ 224
#define TAU_MIN_ 1.0
#define TAU_MAX_ 60.0
#define T_ 8          // ntau
#define A_ 12         // num_angles
#define STRIDE_ 2
#define HS_ 112       // (H-1)/stride + 1
#define WS_ 112

// Prologue: compute the 96 (y,x) offsets in double precision, matching
// numpy's float64 computation then cast to float32.
// Layout in d_ws: offs[0..95] = y, offs[96..191] = x, index k = a*T + t.
__global__ void lp_offsets_kernel(float* __restrict__ offs) {
    int k = threadIdx.x;
    if (k >= A_ * T_) return;
    int a = k / T_;
    int t = k % T_;
    double step = 2.0 * M_PI / (double)A_;
    double theta = (double)a * step - M_PI;
    double c = pow(TAU_MAX_ / TAU_MIN_, 1.0 / (double)(T_ - 1)) - 1.0;
    double tau = TAU_MIN_ * pow(1.0 + c, (double)t);
    offs[k]           = (float)(tau * sin(theta));
    offs[A_ * T_ + k] = (float)(tau * cos(theta));
}

// Main: one thread computes 4 consecutive output columns (float4 store).
// Output index (b, f, t, a, i, j), j fastest.
__global__ __launch_bounds__(256) void lp_sample_kernel(
    const float* __restrict__ inp,
    const float* __restrict__ offs,
    float* __restrict__ out) {

    const int W4 = WS_ / 4;  // 28 float4 per row
    int v = blockIdx.x * blockDim.x + threadIdx.x;

    int j4 = v % W4;  int r = v / W4;
    int i  = r % HS_; r /= HS_;
    int a  = r % A_;  r /= A_;
    int t  = r % T_;  r /= T_;
    int f  = r % F_;
    int b  = r / F_;

    int k = a * T_ + t;
    float yo = offs[k];
    float xo = offs[A_ * T_ + k];

    // Row weights — replicate reference's float32 arithmetic exactly:
    // yq = (i*stride as f32) + yo, floor/frac in f32.
    float yq  = (float)(i * STRIDE_) + yo;
    float y0f = floorf(yq);
    float wy  = yq - y0f;
    int   iy0 = (int)y0f;
    int   iy1 = iy0 + 1;
    bool  vy0 = ((unsigned)iy0 < (unsigned)H_);
    bool  vy1 = ((unsigned)iy1 < (unsigned)H_);

    const float* plane = inp + (size_t)(b * F_ + f) * (H_ * W_);
    const float* row0  = plane + iy0 * W_;
    const float* row1  = plane + iy1 * W_;

    float omwy = 1.0f - wy;
    float res[4];
    int j0 = j4 * 4;

#pragma unroll
    for (int u = 0; u < 4; ++u) {
        int   j   = j0 + u;
        float xq  = (float)(j * STRIDE_) + xo;
        float x0f = floorf(xq);
        float wx  = xq - x0f;
        int   ix0 = (int)x0f;
        int   ix1 = ix0 + 1;
        bool  vx0 = ((unsigned)ix0 < (unsigned)W_);
        bool  vx1 = ((unsigned)ix1 < (unsigned)W_);

        float g00 = (vy0 && vx0) ? row0[ix0] : 0.0f;
        float g01 = (vy0 && vx1) ? row0[ix1] : 0.0f;
        float g10 = (vy1 && vx0) ? row1[ix0] : 0.0f;
        float g11 = (vy1 && vx1) ? row1[ix1] : 0.0f;

        float omwx = 1.0f - wx;
        res[u] = omwy * omwx * g00 + omwy * wx * g01
               + wy   * omwx * g10 + wy   * wx * g11;
    }

    float4 o = make_float4(res[0], res[1], res[2], res[3]);
    ((float4*)out)[v] = o;
}

extern "C" void kernel_launch(void* const* d_in, const int* in_sizes, int n_in,
                              void* d_out, int out_size, void* d_ws, size_t ws_size,
                              hipStream_t stream) {
    const float* inp  = (const float*)d_in[0];
    float*       out  = (float*)d_out;
    float*       offs = (float*)d_ws;   // 192 floats

    lp_offsets_kernel<<<1, 128, 0, stream>>>(offs);

    const int total4 = (B_ * F_ * T_ * A_ * HS_ * WS_) / 4;  // 7,225,344
    const int block  = 256;
    const int grid   = total4 / block;                        // 28,224 exact
    lp_sample_kernel<<<grid, block, 0, stream>>>(inp, offs, out);
}

// Round 2
// 180.436 us; speedup vs baseline: 1.6365x; 1.6365x over previous
//
#include <hip/hip_runtime.h>
#include <cmath>

#ifndef M_PI
#define M_PI 3.14159265358979323846
#endif

// Problem constants (fixed by setup_inputs in the reference)
#define B_ 8
#define F_ 3
#define H_ 224
#define W_ 224
#define TAU_MIN_ 1.0
#define TAU_MAX_ 60.0
#define T_ 8          // ntau
#define A_ 12         // num_angles
#define STRIDE_ 2
#define HS_ 112       // (H-1)/stride + 1
#define WS_ 112
#define PLANE_ (H_ * W_)        // 50176
#define SLICE_ (HS_ * WS_)      // 12544

// Prologue: 96 (y,x) offsets in double precision (matches numpy f64 -> f32).
// d_ws layout: offs[0..95] = y, offs[96..191] = x, index k = a*T + t.
__global__ void lp_offsets_kernel(float* __restrict__ offs) {
    int k = threadIdx.x;
    if (k >= A_ * T_) return;
    int a = k / T_;
    int t = k % T_;
    double step = 2.0 * M_PI / (double)A_;
    double theta = (double)a * step - M_PI;
    double c = pow(TAU_MAX_ / TAU_MIN_, 1.0 / (double)(T_ - 1)) - 1.0;
    double tau = TAU_MIN_ * pow(1.0 + c, (double)t);
    offs[k]           = (float)(tau * sin(theta));
    offs[A_ * T_ + k] = (float)(tau * cos(theta));
}

// One thread per output element. Grid: x = 49 blocks over the 112x112 slice,
// y = (t*A + a) in [0,96), z = (b*F + f) in [0,24).
// Consecutive lanes -> consecutive j -> gather addresses stride 8 B:
// each wave-load touches 8 cache lines; the two x-taps share lines (L1 hit).
__global__ __launch_bounds__(256) void lp_sample_kernel(
    const float* __restrict__ inp,
    const float* __restrict__ offs,
    float* __restrict__ out) {

    int idx = blockIdx.x * 256 + threadIdx.x;      // 0..12543 within slice
    int i = idx / WS_;                             // magic-mul division
    int j = idx - i * WS_;

    int y = blockIdx.y;                            // t*A + a
    int t = y / A_;
    int a = y - t * A_;
    int k = a * T_ + t;
    float yo = offs[k];                            // wave-uniform -> scalar
    float xo = offs[A_ * T_ + k];

    // Replicate reference f32 arithmetic: yq = f32(i*2) + yo, floor/frac f32.
    float yq  = (float)(i * STRIDE_) + yo;
    float y0f = floorf(yq);
    float wy  = yq - y0f;
    int   iy0 = (int)y0f;
    int   iy1 = iy0 + 1;
    float vy0 = ((unsigned)iy0 < (unsigned)H_) ? 1.0f : 0.0f;
    float vy1 = ((unsigned)iy1 < (unsigned)H_) ? 1.0f : 0.0f;
    int   cy0 = min(max(iy0, 0), H_ - 1);
    int   cy1 = min(max(iy1, 0), H_ - 1);

    float xq  = (float)(j * STRIDE_) + xo;
    float x0f = floorf(xq);
    float wx  = xq - x0f;
    int   ix0 = (int)x0f;
    int   ix1 = ix0 + 1;
    float vx0 = ((unsigned)ix0 < (unsigned)W_) ? 1.0f : 0.0f;
    float vx1 = ((unsigned)ix1 < (unsigned)W_) ? 1.0f : 0.0f;
    int   cx0 = min(max(ix0, 0), W_ - 1);
    int   cx1 = min(max(ix1, 0), W_ - 1);

    const float* plane = inp + (size_t)blockIdx.z * PLANE_;

    // Four unconditional loads (clamped addresses) -> all in flight together.
    float g00 = plane[cy0 * W_ + cx0];
    float g01 = plane[cy0 * W_ + cx1];
    float g10 = plane[cy1 * W_ + cx0];
    float g11 = plane[cy1 * W_ + cx1];

    float omwy = 1.0f - wy;
    float omwx = 1.0f - wx;
    float w00 = omwy * omwx, w01 = omwy * wx;
    float w10 = wy * omwx,   w11 = wy * wx;

    float res = w00 * (g00 * (vy0 * vx0)) + w01 * (g01 * (vy0 * vx1))
              + w10 * (g10 * (vy1 * vx0)) + w11 * (g11 * (vy1 * vx1));

    out[((size_t)blockIdx.z * (T_ * A_) + y) * SLICE_ + idx] = res;
}

extern "C" void kernel_launch(void* const* d_in, const int* in_sizes, int n_in,
                              void* d_out, int out_size, void* d_ws, size_t ws_size,
                              hipStream_t stream) {
    const float* inp  = (const float*)d_in[0];
    float*       out  = (float*)d_out;
    float*       offs = (float*)d_ws;   // 192 floats

    lp_offsets_kernel<<<1, 128, 0, stream>>>(offs);

    dim3 grid(SLICE_ / 256, T_ * A_, B_ * F_);   // 49 x 96 x 24
    lp_sample_kernel<<<grid, 256, 0, stream>>>(inp, offs, out);
}

// Round 3
// 158.636 us; speedup vs baseline: 1.8614x; 1.1374x over previous
//
#include <hip/hip_runtime.h>
#include <cmath>

#ifndef M_PI
#define M_PI 3.14159265358979323846
#endif

// Problem constants (fixed by setup_inputs in the reference)
#define B_ 8
#define F_ 3
#define H_ 224
#define W_ 224
#define T_ 8          // ntau
#define A_ 12         // num_angles
#define NK 96         // T_*A_
#define STRIDE_ 2
#define HS_ 112
#define WS_ 112
#define PLANE_ (H_ * W_)        // 50176
#define SLICE_ (HS_ * WS_)      // 12544

// Per-offset constants, computed once on host in f64 (glibc libm, same family
// as numpy's) then split into integer base + f32 fraction. Indexed by
// y = t*A + a (output enumeration order). Passed to the kernel BY VALUE
// (kernarg segment -> scalar loads). Exact-f32 replication of the reference's
// per-element floor/frac is unnecessary: bilinear+zero-pad is continuous in
// the offsets, so <=2.4e-5 weight perturbations give ~1e-4 output deltas.
struct LPArgs {
    int   cx[NK];
    int   cy[NK];
    float fx[NK];
    float fy[NK];
};

static LPArgs make_args() {
    LPArgs r;
    double c = pow(60.0, 1.0 / 7.0) - 1.0;   // (tau_max/tau_min)^(1/(ntau-1)) - 1
    for (int t = 0; t < T_; ++t) {
        double tau = pow(1.0 + c, (double)t);
        for (int ang = 0; ang < A_; ++ang) {
            double theta = (double)ang * (2.0 * M_PI / (double)A_) - M_PI;
            float yo = (float)(tau * sin(theta));
            float xo = (float)(tau * cos(theta));
            int y = t * A_ + ang;
            float yf = floorf(yo), xf = floorf(xo);
            r.cy[y] = (int)yf; r.fy[y] = yo - yf;
            r.cx[y] = (int)xf; r.fx[y] = xo - xf;
        }
    }
    return r;
}

// Grid: (7 i-tiles, 96 offsets, 24 planes), block 256.
// Lane j = tid&127 (j<112 active), iband = tid>>7 (wave-uniform).
// Thread handles rows i = tile*16 + iband + 2s, s=0..7: all y-side math is
// wave-uniform -> SALU; taps live at immediate offsets 0,4,896,900 from one
// vector address. Inner loop ~8 VALU + 4 loads + 1 store per output.
__global__ __launch_bounds__(256) void lp_sample_kernel(
    const float* __restrict__ inp, float* __restrict__ out, LPArgs args) {

    const int y  = blockIdx.y;                         // t*A + a
    const int bf = blockIdx.z;                         // b*F + f
    const int j  = threadIdx.x & 127;
    const int iband = __builtin_amdgcn_readfirstlane(threadIdx.x >> 7);

    const int   cx = args.cx[y];
    const float fx = args.fx[y];
    const int   cy = args.cy[y];
    const float fy = args.fy[y];

    // x-side (per thread, once): taps are columns {ix0, ix0+1}; we always
    // load the safe pair {bx, bx+1} and fold validity/alignment into (wA,wB).
    int ix0 = STRIDE_ * j + cx;
    int bx  = min(max(ix0, 0), W_ - 2);
    float wA, wB;
    if (ix0 >= 0 && ix0 <= W_ - 2)  { wA = 1.0f - fx; wB = fx; }
    else if (ix0 == -1)             { wA = fx;        wB = 0.0f; }  // pair {0,1}: g.x is the ix1 tap
    else if (ix0 == W_ - 1)         { wA = 0.0f;      wB = 1.0f - fx; } // pair {222,223}: g.y is the ix0 tap
    else                            { wA = 0.0f;      wB = 0.0f; }

    const float* plane = inp + (size_t)bf * PLANE_;
    const int i0 = blockIdx.x * 16 + iband;
    float* orow = out + ((size_t)bf * NK + y) * SLICE_ + (size_t)i0 * WS_ + j;

    const bool active = (j < WS_);

#pragma unroll
    for (int s = 0; s < 8; ++s) {
        int iy0 = STRIDE_ * (i0 + 2 * s) + cy;          // wave-uniform
        float mA, mB;
        if (iy0 >= 0 && iy0 <= H_ - 2)  { mA = 1.0f - fy; mB = fy; }
        else if (iy0 == -1)             { mA = fy;        mB = 0.0f; }
        else if (iy0 == H_ - 1)         { mA = 0.0f;      mB = 1.0f - fy; }
        else                            { mA = 0.0f;      mB = 0.0f; }
        int by = min(max(iy0, 0), H_ - 2);              // rows {by, by+1} always safe

        const float* p = plane + by * W_ + bx;
        float g0x = p[0],  g0y = p[1];
        float g1x = p[W_], g1y = p[W_ + 1];

        float h0 = wA * g0x + wB * g0y;
        float h1 = wA * g1x + wB * g1y;
        float r  = mA * h0 + mB * h1;

        if (active) orow[s * 2 * WS_] = r;
    }
}

extern "C" void kernel_launch(void* const* d_in, const int* in_sizes, int n_in,
                              void* d_out, int out_size, void* d_ws, size_t ws_size,
                              hipStream_t stream) {
    const float* inp = (const float*)d_in[0];
    float*       out = (float*)d_out;

    static const LPArgs args = make_args();   // host-side, once; capture-safe

    dim3 grid(HS_ / 16, NK, B_ * F_);         // 7 x 96 x 24
    lp_sample_kernel<<<grid, 256, 0, stream>>>(inp, out, args);
}

// Round 4
// 154.361 us; speedup vs baseline: 1.9130x; 1.0277x over previous
//
#include <hip/hip_runtime.h>
#include <cmath>

#ifndef M_PI
#define M_PI 3.14159265358979323846
#endif

// Problem constants (fixed by setup_inputs in the reference)
#define B_ 8
#define F_ 3
#define H_ 224
#define W_ 224
#define T_ 8          // ntau
#define A_ 12         // num_angles
#define NK 96         // T_*A_
#define STRIDE_ 2
#define HS_ 112
#define WS_ 112
#define PLANE_ (H_ * W_)        // 50176
#define SLICE_ (HS_ * WS_)      // 12544

// Per-offset constants, computed once on host in f64 then split into
// integer base + f32 fraction. Indexed by y = t*A + a. Passed BY VALUE
// (kernarg -> scalar loads). Bilinear+zero-pad is continuous in the offsets,
// so per-offset (vs per-element f32) floor/frac gives ~1e-2 deltas << 9.3e-2
// threshold (validated R3: absmax 1.6e-2).
struct LPArgs {
    int   cx[NK];
    int   cy[NK];
    float fx[NK];
    float fy[NK];
};

static LPArgs make_args() {
    LPArgs r;
    double c = pow(60.0, 1.0 / 7.0) - 1.0;   // (tau_max/tau_min)^(1/(ntau-1)) - 1
    for (int t = 0; t < T_; ++t) {
        double tau = pow(1.0 + c, (double)t);
        for (int ang = 0; ang < A_; ++ang) {
            double theta = (double)ang * (2.0 * M_PI / (double)A_) - M_PI;
            float yo = (float)(tau * sin(theta));
            float xo = (float)(tau * cos(theta));
            int y = t * A_ + ang;
            float yf = floorf(yo), xf = floorf(xo);
            r.cy[y] = (int)yf; r.fy[y] = yo - yf;
            r.cx[y] = (int)xf; r.fx[y] = xo - xf;
        }
    }
    return r;
}

// float2 with alignment 4: tap pairs start at column 2j+cx, misaligned by
// 4 B when cx is odd. amdhsa default enables unaligned global access; worst
// case the compiler splits into 2 dwords (== old behavior).
typedef float f2v __attribute__((ext_vector_type(2)));
typedef f2v uf2 __attribute__((aligned(4)));

// Grid: (24 planes, 96 offsets, 7 i-tiles), block 256.
// Plane on gridDim.x (24 % 8 == 0): round-robin block->XCD puts only 3
// planes (600 KB) on each XCD -> input fully L2-resident per XCD.
// Lane j = tid&127 (j<112 active), iband = tid>>7 (wave-uniform).
// Per output: 2 float2 loads (row tap-pairs; adjacent lanes tile the row
// exactly -> zero byte duplication) + ~6 VALU + 1 store. All y-side math
// is wave-uniform -> SALU.
__global__ __launch_bounds__(256) void lp_sample_kernel(
    const float* __restrict__ inp, float* __restrict__ out, LPArgs args) {

    const int bf = blockIdx.x;                         // b*F + f
    const int y  = blockIdx.y;                         // t*A + a
    const int j  = threadIdx.x & 127;
    const int iband = __builtin_amdgcn_readfirstlane(threadIdx.x >> 7);

    const int   cx = args.cx[y];
    const float fx = args.fx[y];
    const int   cy = args.cy[y];
    const float fy = args.fy[y];

    // x-side (per thread, once): always load the safe pair {bx, bx+1},
    // fold validity/alignment into (wA, wB).
    int ix0 = STRIDE_ * j + cx;
    int bx  = min(max(ix0, 0), W_ - 2);
    float wA, wB;
    if (ix0 >= 0 && ix0 <= W_ - 2)  { wA = 1.0f - fx; wB = fx; }
    else if (ix0 == -1)             { wA = fx;        wB = 0.0f; }
    else if (ix0 == W_ - 1)         { wA = 0.0f;      wB = 1.0f - fx; }
    else                            { wA = 0.0f;      wB = 0.0f; }

    const float* plane = inp + (size_t)bf * PLANE_;
    const int i0 = blockIdx.z * 16 + iband;
    float* orow = out + ((size_t)bf * NK + y) * SLICE_ + (size_t)i0 * WS_ + j;

    const bool active = (j < WS_);

#pragma unroll
    for (int s = 0; s < 8; ++s) {
        int iy0 = STRIDE_ * (i0 + 2 * s) + cy;          // wave-uniform
        float mA, mB;
        if (iy0 >= 0 && iy0 <= H_ - 2)  { mA = 1.0f - fy; mB = fy; }
        else if (iy0 == -1)             { mA = fy;        mB = 0.0f; }
        else if (iy0 == H_ - 1)         { mA = 0.0f;      mB = 1.0f - fy; }
        else                            { mA = 0.0f;      mB = 0.0f; }
        int by = min(max(iy0, 0), H_ - 2);              // rows {by, by+1} safe

        const float* p = plane + by * W_ + bx;
        f2v r0 = *(const uf2*)p;          // columns {bx, bx+1}, row by
        f2v r1 = *(const uf2*)(p + W_);   // columns {bx, bx+1}, row by+1

        float h0 = wA * r0.x + wB * r0.y;
        float h1 = wA * r1.x + wB * r1.y;
        float r  = mA * h0 + mB * h1;

        if (active) orow[s * 2 * WS_] = r;
    }
}

extern "C" void kernel_launch(void* const* d_in, const int* in_sizes, int n_in,
                              void* d_out, int out_size, void* d_ws, size_t ws_size,
                              hipStream_t stream) {
    const float* inp = (const float*)d_in[0];
    float*       out = (float*)d_out;

    static const LPArgs args = make_args();   // host-side, once; capture-safe

    dim3 grid(B_ * F_, NK, HS_ / 16);         // 24 x 96 x 7
    lp_sample_kernel<<<grid, 256, 0, stream>>>(inp, out, args);
}

// Round 5
// 153.016 us; speedup vs baseline: 1.9298x; 1.0088x over previous
//
#include <hip/hip_runtime.h>
#include <cmath>

#ifndef M_PI
#define M_PI 3.14159265358979323846
#endif

// Problem constants (fixed by setup_inputs in the reference)
#define B_ 8
#define F_ 3
#define H_ 224
#define W_ 224
#define T_ 8          // ntau
#define A_ 12         // num_angles
#define NK 96         // T_*A_
#define STRIDE_ 2
#define HS_ 112
#define WS_ 112
#define PLANE_ (H_ * W_)        // 50176
#define SLICE_ (HS_ * WS_)      // 12544

#define RI 4                     // output rows per block
#define BAND (2 * RI + 119)      // 127 staged input rows (offsets span [-60,59])

// Per-offset constants, computed once on host in f64 then split into integer
// base + f32 fraction. Indexed by k = t*A + a. Passed BY VALUE (kernarg ->
// scalar loads; k made provably uniform via readfirstlane). Bilinear+zero-pad
// is continuous in the offsets, so per-offset (vs per-element f32) floor/frac
// gives ~1e-2 deltas << 9.3e-2 threshold (validated R3/R4: absmax 1.6e-2).
struct LPArgs {
    int   cx[NK];
    int   cy[NK];
    float fx[NK];
    float fy[NK];
};

static LPArgs make_args() {
    LPArgs r;
    double c = pow(60.0, 1.0 / 7.0) - 1.0;
    for (int t = 0; t < T_; ++t) {
        double tau = pow(1.0 + c, (double)t);
        for (int ang = 0; ang < A_; ++ang) {
            double theta = (double)ang * (2.0 * M_PI / (double)A_) - M_PI;
            float yo = (float)(tau * sin(theta));
            float xo = (float)(tau * cos(theta));
            int k = t * A_ + ang;
            float yf = floorf(yo), xf = floorf(xo);
            r.cy[k] = (int)yf; r.fy[k] = yo - yf;
            r.cx[k] = (int)xf; r.fx[k] = xo - xf;
        }
    }
    return r;
}

// Grid (24 planes, 28 i-tiles), block 1024 (16 waves), LDS 113.8 KB -> 1
// block/CU. Stage the contiguous input row-band once (dense float4 copy),
// then gather from LDS: stride-2-float gathers are 2-way bank aliasing =
// free. Wave w: fixed i = i0 + (w&3), k = (w>>2) + 4n for n=0..23; each k
// does 2 column-halves (j = lane, lane+64). All y-side math wave-uniform.
__global__ __launch_bounds__(1024) void lp_sample_kernel(
    const float* __restrict__ inp, float* __restrict__ out, LPArgs args) {

    __shared__ float lds[BAND * W_];   // 127*224 floats = 113,792 B

    const int bf  = blockIdx.x;                       // b*F + f
    const int i0  = blockIdx.y * RI;
    const int r0  = max(0, 2 * i0 - 60);
    const int r1  = min(H_ - 1, 2 * i0 + 2 * RI + 58);
    const int tid = threadIdx.x;

    const float* plane = inp + (size_t)bf * PLANE_;

    // Dense contiguous staging: rows r0..r1 are one flat global span,
    // 16B-aligned (r0*224*4 % 16 == 0), length multiple of 16 B.
    {
        const float4* src4 = (const float4*)(plane + r0 * W_);
        float4*       dst4 = (float4*)lds;
        const int n4 = (r1 - r0 + 1) * (W_ / 4);      // <= 7112
        for (int v = tid; v < n4; v += 1024) dst4[v] = src4[v];
    }
    __syncthreads();

    const int lane = tid & 63;
    const int wave = __builtin_amdgcn_readfirstlane(tid >> 6);
    const int di   = wave & 3;
    const int kb   = wave >> 2;
    const int i    = i0 + di;

    float* outbase = out + (size_t)bf * NK * SLICE_ + (size_t)i * WS_;

#pragma unroll 1
    for (int n = 0; n < 24; ++n) {
        const int k = kb + 4 * n;                     // uniform (SGPR + literal)
        const int   cy = args.cy[k]; const float fy = args.fy[k];
        const int   cx = args.cx[k]; const float fx = args.fx[k];

        const int iy0 = 2 * i + cy;                   // wave-uniform
        float mA, mB;
        if (iy0 >= 0 && iy0 <= H_ - 2)  { mA = 1.0f - fy; mB = fy; }
        else if (iy0 == -1)             { mA = fy;        mB = 0.0f; }
        else if (iy0 == H_ - 1)         { mA = 0.0f;      mB = 1.0f - fy; }
        else                            { mA = 0.0f;      mB = 0.0f; }
        const int by = min(max(iy0, 0), H_ - 2);
        const float* lrow = lds + (by - r0) * W_;     // rows {by,by+1} staged

        float* orow = outbase + (size_t)k * SLICE_;

#pragma unroll
        for (int h = 0; h < 2; ++h) {
            const int j   = h * 64 + lane;
            const int ix0 = 2 * j + cx;
            float wA, wB;
            if (ix0 >= 0 && ix0 <= W_ - 2)  { wA = 1.0f - fx; wB = fx; }
            else if (ix0 == -1)             { wA = fx;        wB = 0.0f; }
            else if (ix0 == W_ - 1)         { wA = 0.0f;      wB = 1.0f - fx; }
            else                            { wA = 0.0f;      wB = 0.0f; }
            const int bx = min(max(ix0, 0), W_ - 2);

            float g00 = lrow[bx],      g01 = lrow[bx + 1];       // ds_read2
            float g10 = lrow[W_ + bx], g11 = lrow[W_ + bx + 1];  // ds_read2

            float r = mA * (wA * g00 + wB * g01)
                    + mB * (wA * g10 + wB * g11);

            if (h == 0 || j < WS_) orow[j] = r;       // h=0 always active
        }
    }
}

extern "C" void kernel_launch(void* const* d_in, const int* in_sizes, int n_in,
                              void* d_out, int out_size, void* d_ws, size_t ws_size,
                              hipStream_t stream) {
    const float* inp = (const float*)d_in[0];
    float*       out = (float*)d_out;

    static const LPArgs args = make_args();   // host-side, once; capture-safe

    dim3 grid(B_ * F_, HS_ / RI);             // 24 x 28
    lp_sample_kernel<<<grid, 1024, 0, stream>>>(inp, out, args);
}

// Round 6
// 134.382 us; speedup vs baseline: 2.1974x; 1.1387x over previous
//
#include <hip/hip_runtime.h>
#include <cmath>
#include <algorithm>

#ifndef M_PI
#define M_PI 3.14159265358979323846
#endif

// Problem constants (fixed by setup_inputs in the reference)
#define B_ 8
#define F_ 3
#define H_ 224
#define W_ 224
#define T_ 8          // ntau
#define A_ 12         // num_angles
#define NK 96         // T_*A_
#define STRIDE_ 2
#define HS_ 112
#define WS_ 112
#define PLANE_ (H_ * W_)        // 50176
#define SLICE_ (HS_ * WS_)      // 12544

#define RI 4                     // output rows per block
#define BANDMAX 70               // staged rows per group-band (<=68 actual)

// Per-offset constants (host, f64) reordered into two cy-sorted groups of 48
// so each group's row-band fits 61 KB LDS -> 2 blocks/CU. korig maps back to
// the output's k = t*A + a index. Per-offset (vs per-element f32) floor/frac
// is continuity-safe: validated R3-R5, absmax 1.6e-2 << 9.3e-2.
struct LPArgs {
    int   cy[NK];  int cx[NK];
    float fy[NK];  float fx[NK];
    int   korig[NK];
    int   cymin[2]; int cymax[2];
};

static LPArgs make_args() {
    int cy[NK], cx[NK]; float fy[NK], fx[NK];
    double c = pow(60.0, 1.0 / 7.0) - 1.0;
    for (int t = 0; t < T_; ++t) {
        double tau = pow(1.0 + c, (double)t);
        for (int a = 0; a < A_; ++a) {
            double th = (double)a * (2.0 * M_PI / (double)A_) - M_PI;
            float yo = (float)(tau * sin(th)), xo = (float)(tau * cos(th));
            int k = t * A_ + a;
            float yf = floorf(yo), xf = floorf(xo);
            cy[k] = (int)yf; fy[k] = yo - yf;
            cx[k] = (int)xf; fx[k] = xo - xf;
        }
    }
    int idx[NK];
    for (int k = 0; k < NK; ++k) idx[k] = k;
    std::sort(idx, idx + NK, [&](int a, int b) { return cy[a] < cy[b]; });
    LPArgs r;
    r.cymin[0] = r.cymin[1] = 1000; r.cymax[0] = r.cymax[1] = -1000;
    for (int p = 0; p < NK; ++p) {
        int k = idx[p], g = p / 48;
        r.cy[p] = cy[k]; r.cx[p] = cx[k];
        r.fy[p] = fy[k]; r.fx[p] = fx[k];
        r.korig[p] = k;
        r.cymin[g] = std::min(r.cymin[g], cy[k]);
        r.cymax[g] = std::max(r.cymax[g], cy[k]);
    }
    return r;
}

// Grid (24 planes, 28 i-tiles, 2 cy-groups), block 1024 (16 waves),
// LDS 62.7 KB -> 2 blocks/CU (staging of one block overlaps compute of the
// co-resident one). Wave-task = (k, column-half): the x-side select/clamp,
// LDS column addr, and 64-bit store base are computed ONCE per task, then
// RI=4 row iterations are 1 v_add + 2 ds_read2_b32 + 6 FMA + 1 store each
// (stores via immediate offsets di*448). All y-side math wave-uniform->SALU.
__global__ __launch_bounds__(1024) void lp_sample_kernel(
    const float* __restrict__ inp, float* __restrict__ out, LPArgs args) {

    __shared__ float lds[BANDMAX * W_];   // 70*224*4 = 62,720 B

    const int bf = blockIdx.x;            // b*F + f
    const int i0 = blockIdx.y * RI;
    const int g  = blockIdx.z;

    const int r0 = max(0, 2 * i0 + args.cymin[g]);
    const int r1 = min(H_ - 1, 2 * i0 + 2 * (RI - 1) + args.cymax[g] + 1);

    const float* plane = inp + (size_t)bf * PLANE_;
    {   // dense contiguous staging (16B-aligned span, multiple of 16 B)
        const float4* s4 = (const float4*)(plane + r0 * W_);
        float4*       d4 = (float4*)lds;
        const int n4 = (r1 - r0 + 1) * (W_ / 4);      // <= 3808
        for (int v = threadIdx.x; v < n4; v += 1024) d4[v] = s4[v];
    }
    __syncthreads();

    const int lane = threadIdx.x & 63;
    const int wave = __builtin_amdgcn_readfirstlane(threadIdx.x >> 6);

    float* outp = out + (size_t)bf * (NK * SLICE_) + (size_t)i0 * WS_;

#pragma unroll 1
    for (int tt = 0; tt < 6; ++tt) {
        const int task = wave + (tt << 4);            // 0..95
        const int kl   = task >> 1;                   // 0..47 within group
        const int h    = task & 1;                    // column half
        const int kk   = g * 48 + kl;

        const int   cy = args.cy[kk]; const float fy = args.fy[kk];
        const int   cx = args.cx[kk]; const float fx = args.fx[kk];
        const int   ko = args.korig[kk];

        // --- per-task x-side setup (amortized over RI rows) ---
        const int j   = h * 64 + lane;
        const int ix0 = 2 * j + cx;
        float wA, wB;
        if (ix0 >= 0 && ix0 <= W_ - 2)  { wA = 1.0f - fx; wB = fx; }
        else if (ix0 == -1)             { wA = fx;        wB = 0.0f; }
        else if (ix0 == W_ - 1)         { wA = 0.0f;      wB = 1.0f - fx; }
        else                            { wA = 0.0f;      wB = 0.0f; }
        const int bx = min(max(ix0, 0), W_ - 2);
        const float* lcol = lds + bx;                 // vector part of LDS addr

        float* orow = outp + (size_t)ko * SLICE_ + j;
        const bool act = (j < WS_);

#pragma unroll
        for (int di = 0; di < RI; ++di) {
            const int iy0 = 2 * (i0 + di) + cy;       // wave-uniform
            float mA, mB;
            if (iy0 >= 0 && iy0 <= H_ - 2)  { mA = 1.0f - fy; mB = fy; }
            else if (iy0 == -1)             { mA = fy;        mB = 0.0f; }
            else if (iy0 == H_ - 1)         { mA = 0.0f;      mB = 1.0f - fy; }
            else                            { mA = 0.0f;      mB = 0.0f; }
            const int by = min(max(iy0, 0), H_ - 2);  // rows {by,by+1} staged

            const float* p = lcol + (by - r0) * W_;   // 1 v_add (uniform srcs folded)
            float g00 = p[0],   g01 = p[1];           // ds_read2_b32 0/1
            float g10 = p[W_],  g11 = p[W_ + 1];      // ds_read2_b32 224/225

            float r = mA * (wA * g00 + wB * g01)
                    + mB * (wA * g10 + wB * g11);

            if (act) orow[(size_t)di * WS_] = r;      // imm offset di*448
        }
    }
}

extern "C" void kernel_launch(void* const* d_in, const int* in_sizes, int n_in,
                              void* d_out, int out_size, void* d_ws, size_t ws_size,
                              hipStream_t stream) {
    const float* inp = (const float*)d_in[0];
    float*       out = (float*)d_out;

    static const LPArgs args = make_args();   // host-side, once; capture-safe

    dim3 grid(B_ * F_, HS_ / RI, 2);          // 24 x 28 x 2
    lp_sample_kernel<<<grid, 1024, 0, stream>>>(inp, out, args);
}